// Round 21
// baseline (169.379 us; speedup 1.0000x reference)
//
#include <hip/hip_runtime.h>

typedef __bf16 bf16;
typedef __bf16 bf16x4 __attribute__((ext_vector_type(4)));
typedef __bf16 bf16x8 __attribute__((ext_vector_type(8)));
typedef short  s16x4  __attribute__((ext_vector_type(4)));
typedef float  f32x4  __attribute__((ext_vector_type(4)));

#define VOC 65

// Compiler-only ordering barrier (R20-verified: HW LDS is in-order per wave).
#define LDS_FENCE() asm volatile("" ::: "memory")

// workspace layout (element offsets, bf16)
#define WS_WQ 0
#define WS_WK 16384
#define WS_WV 32768
#define WS_WO 49152
#define WS_W1 65536
#define WS_W2 196608
#define WS_WF 327680   // padded [80][32]

// ---------------- prep kernels: f32 -> bf16 transpose to [col][k] (k contiguous) ----------------
__global__ void transpose_f32bf16_k(const float* __restrict__ src, bf16* __restrict__ dst,
                                    int batch, int R, int C) {
  int i = blockIdx.x * blockDim.x + threadIdx.x;
  int total = batch * R * C;
  if (i >= total) return;
  int b = i / (R * C);
  int rc = i - b * (R * C);
  int r = rc / C;
  int c = rc - r * C;
  dst[(b * C + c) * R + r] = (bf16)src[i];   // [b][R][C] -> [b][C][R]
}

__global__ void prep_wf_k(const float* __restrict__ wf, bf16* __restrict__ dst) {
  int i = blockIdx.x * blockDim.x + threadIdx.x;  // 80*32
  if (i >= 80 * 32) return;
  int c = i >> 5, r = i & 31;
  dst[i] = (c < VOC) ? (bf16)wf[r * VOC + c] : (bf16)0.0f;  // [80 cols][32 k], cols 65..79 zero
}

// ---------------- fused transformer ----------------
// R21 = R20 + batch-issued attention weight loads (all head weights in flight
// before the MFMA chain; FFN-style latency hiding applied to attention).

#define MFMA32(a,b,c) __builtin_amdgcn_mfma_f32_16x16x32_bf16((a),(b),(c),0,0,0)

static __device__ __forceinline__ f32x4 MFMA16(bf16x4 a, bf16x4 b, f32x4 c) {
  return __builtin_amdgcn_mfma_f32_16x16x16bf16_1k(
      __builtin_bit_cast(s16x4, a), __builtin_bit_cast(s16x4, b), c, 0, 0, 0);
}

static __device__ __forceinline__ f32x4 splat4(float v) {
  f32x4 s; s[0] = v; s[1] = v; s[2] = v; s[3] = v; return s;
}

#define NS 4   // seqs per wave

__global__ __launch_bounds__(128)
void xformer_k(const int* __restrict__ x, const float* __restrict__ emb, const float* __restrict__ pos,
               const float* __restrict__ bq, const float* __restrict__ bk, const float* __restrict__ bv,
               const float* __restrict__ bo, const float* __restrict__ ga, const float* __restrict__ ba,
               const float* __restrict__ b1, const float* __restrict__ b2,
               const float* __restrict__ gm, const float* __restrict__ bm,
               const float* __restrict__ bfin,
               const bf16* __restrict__ ws, float* __restrict__ out)
{
  __shared__ bf16 mbuf[2][NS][16][72];  // [wave][si][tok][hid], two 32-col parity windows
  __shared__ bf16 hbnc[2][NS][16][40];  // [wave][si][tok][dim] LN transpose bounce
  const int tid  = threadIdx.x;
  const int wv   = tid >> 6;
  const int lane = tid & 63;
  const int lo   = lane & 15;
  const int hi   = lane >> 4;           // 0..3
  const int seq0 = blockIdx.x * (2*NS) + wv * NS;

  const bf16* wqT = ws + WS_WQ;         // [l*4+h][64 out][32 k]
  const bf16* wkT = ws + WS_WK;
  const bf16* wvT = ws + WS_WV;
  const bf16* woT = ws + WS_WO;         // [l][32 out][256 hv]
  const bf16* w1T = ws + WS_W1;         // [l][2048 hid][32 k]
  const bf16* w2T = ws + WS_W2;         // [l][32 out][2048 hid]
  const bf16* wfT = ws + WS_WF;         // [80 voc][32 k]

  const f32x4 fz = {0.f, 0.f, 0.f, 0.f};

  // Register state per seq:
  //  bh : h as MFMA32 A/B-frag  [tok=lo][dim=hi*8+j]
  //  hD0: h[tok=4hi+r][dim=lo], hD1: [dim=16+lo]  (residual copy, D-layout)
  bf16x8 bh[NS];
  bf16x4 hD0[NS], hD1[NS];

  // ---- embedding: h = (emb[x] + pos) * sqrt(32), straight to registers ----
  #pragma unroll
  for (int si = 0; si < NS; ++si) {
    const int s = seq0 + si;
    int idl = x[s*16 + lo];
    idl = idl < 0 ? 0 : (idl >= VOC ? VOC - 1 : idl);
    f32x4 e0 = *(const f32x4*)(emb + idl*32 + hi*8);
    f32x4 e1 = *(const f32x4*)(emb + idl*32 + hi*8 + 4);
    f32x4 p0 = *(const f32x4*)(pos + lo*32 + hi*8);
    f32x4 p1 = *(const f32x4*)(pos + lo*32 + hi*8 + 4);
    bf16x8 hv;
    #pragma unroll
    for (int j = 0; j < 4; ++j) {
      hv[j]   = (bf16)((e0[j] + p0[j]) * 5.656854249492381f);
      hv[4+j] = (bf16)((e1[j] + p1[j]) * 5.656854249492381f);
    }
    bh[si] = hv;
    bf16x4 d0, d1;
    #pragma unroll
    for (int r = 0; r < 4; ++r) {
      int tr = hi*4 + r;
      int idr = x[s*16 + tr];
      idr = idr < 0 ? 0 : (idr >= VOC ? VOC - 1 : idr);
      d0[r] = (bf16)((emb[idr*32 + lo]      + pos[tr*32 + lo])      * 5.656854249492381f);
      d1[r] = (bf16)((emb[idr*32 + 16 + lo] + pos[tr*32 + 16 + lo]) * 5.656854249492381f);
    }
    hD0[si] = d0; hD1[si] = d1;
  }

  for (int l = 0; l < 2; ++l) {
    // ================= attention: all-register, batch-loaded weights =================
    f32x4 accO[NS][2];                  // D: [tok=4hi+r][out=n2*16+lo], bo in C
    {
      float bo0 = bo[l*32 + lo], bo1 = bo[l*32 + 16 + lo];
      #pragma unroll
      for (int si = 0; si < NS; ++si) { accO[si][0] = splat4(bo0); accO[si][1] = splat4(bo1); }
    }
    #pragma unroll
    for (int hh = 0; hh < 4; ++hh) {
      const int hb = (l*4 + hh) * 64;
      // ---- batch-issue ALL weight/bias loads for this head (stay in flight) ----
      bf16x8 wq8[4], wk8[4], wv8[4];
      bf16x4 wo4[4][2];
      f32x4 bq4[4], bk4[4], bv4[4];
      #pragma unroll
      for (int nt = 0; nt < 4; ++nt) {
        const int wofs = (hb + nt*16 + lo)*32 + hi*8;
        wq8[nt] = *(const bf16x8*)(wqT + wofs);
        wk8[nt] = *(const bf16x8*)(wkT + wofs);
        wv8[nt] = *(const bf16x8*)(wvT + wofs);
        wo4[nt][0] = *(const bf16x4*)(woT + (l*32 + lo)*256      + hh*64 + nt*16 + hi*4);
        wo4[nt][1] = *(const bf16x4*)(woT + (l*32 + 16 + lo)*256 + hh*64 + nt*16 + hi*4);
        bq4[nt] = *(const f32x4*)(bq + hb + nt*16 + hi*4);
        bk4[nt] = *(const f32x4*)(bk + hb + nt*16 + hi*4);
        bv4[nt] = splat4(bv[hb + nt*16 + lo]);
      }
      // ---- Q,K proj (swapped MFMA32, bias in C) fused into scores (MFMA16 chain) ----
      f32x4 sf[NS];
      #pragma unroll
      for (int si = 0; si < NS; ++si) sf[si] = fz;
      #pragma unroll
      for (int nt = 0; nt < 4; ++nt) {
        #pragma unroll
        for (int si = 0; si < NS; ++si) {
          f32x4 dq = MFMA32(wq8[nt], bh[si], bq4[nt]);  // Q[out=nt16+4hi+r][tok=lo]
          f32x4 dk = MFMA32(wk8[nt], bh[si], bk4[nt]);
          bf16x4 pq, pk;
          #pragma unroll
          for (int r = 0; r < 4; ++r) {
            pq[r] = (bf16)dq[r];
            pk[r] = (bf16)dk[r];
          }
          sf[si] = MFMA16(pk, pq, sf[si]);      // S[key=4hi+r][query=lo]
        }
      }
      // ---- softmax (no-max: scores O(1), exp can't overflow; mask -> exp(-30)~0) ----
      bf16x4 pp[NS];
      #pragma unroll
      for (int si = 0; si < NS; ++si) {
        float e[4], sm = 0.f;
        #pragma unroll
        for (int r = 0; r < 4; ++r) {
          int key = hi*4 + r;
          float v0 = (key <= lo) ? sf[si][r] * 0.125f : -30.0f;
          e[r] = __expf(v0);
          sm += e[r];
        }
        sm += __shfl_xor(sm, 16);
        sm += __shfl_xor(sm, 32);
        float inv = 1.0f / sm;
        bf16x4 p4;
        #pragma unroll
        for (int r = 0; r < 4; ++r) p4[r] = (bf16)(e[r] * inv);
        pp[si] = p4;                            // B-frag [col=query=lo][k=key 4hi+j]
      }
      // ---- V proj (original, bias in C) + PV + out-proj (register-chained) ----
      #pragma unroll
      for (int nt = 0; nt < 4; ++nt) {
        #pragma unroll
        for (int si = 0; si < NS; ++si) {
          f32x4 dv = MFMA32(bh[si], wv8[nt], bv4[nt]);  // V[tok=4hi+r][vdim=nt16+lo]
          bf16x4 vz;
          #pragma unroll
          for (int r = 0; r < 4; ++r) vz[r] = (bf16)dv[r];
          f32x4 o = MFMA16(vz, pp[si], fz);     // O[vdim=nt16+4hi+r][tok=lo]
          bf16x4 oz;
          #pragma unroll
          for (int r = 0; r < 4; ++r) oz[r] = (bf16)o[r];
          #pragma unroll
          for (int n2 = 0; n2 < 2; ++n2)
            accO[si][n2] = MFMA16(oz, wo4[nt][n2], accO[si][n2]);  // [tok=4hi+r][out=n2*16+lo]
        }
      }
    }
    // ---- residual + LN(ga,ba) (bo already in accO); rebuild bh via wave-private bounce ----
    {
      float g0 = ga[l*32 + lo], g1 = ga[l*32 + 16 + lo];
      float a0 = ba[l*32 + lo], a1 = ba[l*32 + 16 + lo];
      #pragma unroll
      for (int si = 0; si < NS; ++si) {
        bf16x4 nh0, nh1;
        #pragma unroll
        for (int r = 0; r < 4; ++r) {
          float v0 = accO[si][0][r] + (float)hD0[si][r];
          float v1 = accO[si][1][r] + (float)hD1[si][r];
          float s1 = v0 + v1, s2 = v0*v0 + v1*v1;
          s1 += __shfl_xor(s1, 1); s2 += __shfl_xor(s2, 1);
          s1 += __shfl_xor(s1, 2); s2 += __shfl_xor(s2, 2);
          s1 += __shfl_xor(s1, 4); s2 += __shfl_xor(s2, 4);
          s1 += __shfl_xor(s1, 8); s2 += __shfl_xor(s2, 8);
          float mean = s1 * (1.f/32.f);
          float var  = s2 * (1.f/32.f) - mean*mean;
          float rs   = rsqrtf(fabsf(var) + 1e-5f);
          float h0 = (v0 - mean)*rs*g0 + a0;
          float h1 = (v1 - mean)*rs*g1 + a1;
          nh0[r] = (bf16)h0; nh1[r] = (bf16)h1;
          hbnc[wv][si][hi*4 + r][lo]      = (bf16)h0;
          hbnc[wv][si][hi*4 + r][16 + lo] = (bf16)h1;
        }
        hD0[si] = nh0; hD1[si] = nh1;
      }
      LDS_FENCE();
      #pragma unroll
      for (int si = 0; si < NS; ++si)
        bh[si] = *(const bf16x8*)(&hbnc[wv][si][lo][hi*8]);
      LDS_FENCE();
    }
    // ================= FFN: LDS-bounce MFMA32, 2-deep prefetch, unroll-2 =================
    f32x4 acc2[NS][2];                  // D: [tok=4hi+r][out=n2*16+lo], b2 in C
    {
      float b20 = b2[l*32 + lo], b21 = b2[l*32 + 16 + lo];
      #pragma unroll
      for (int si = 0; si < NS; ++si) { acc2[si][0] = splat4(b20); acc2[si][1] = splat4(b21); }
    }
    const bf16* w1l = w1T + l*65536;
    const bf16* w2l = w2T + l*65536;
    const float* b1l = b1 + l*2048;
    // preload set A (kk=0) and set B (kk=1)
    bf16x8 A10 = *(const bf16x8*)(w1l + (lo)*32 + hi*8);
    bf16x8 A11 = *(const bf16x8*)(w1l + (16 + lo)*32 + hi*8);
    bf16x8 A20 = *(const bf16x8*)(w2l + (lo)*2048 + hi*8);
    bf16x8 A21 = *(const bf16x8*)(w2l + (16 + lo)*2048 + hi*8);
    f32x4  Ab0 = *(const f32x4*)(b1l + hi*4);
    f32x4  Ab1 = *(const f32x4*)(b1l + 16 + hi*4);
    bf16x8 B10 = *(const bf16x8*)(w1l + (32 + lo)*32 + hi*8);
    bf16x8 B11 = *(const bf16x8*)(w1l + (48 + lo)*32 + hi*8);
    bf16x8 B20 = *(const bf16x8*)(w2l + (lo)*2048 + 32 + hi*8);
    bf16x8 B21 = *(const bf16x8*)(w2l + (16 + lo)*2048 + 32 + hi*8);
    f32x4  Bb0 = *(const f32x4*)(b1l + 32 + hi*4);
    f32x4  Bb1 = *(const f32x4*)(b1l + 32 + 16 + hi*4);
    for (int kk = 0; kk < 64; kk += 2) {
      // ======== even half: uses set A (window 0); prefetch A <- kk+2 ========
      {
        const int k2 = (kk + 2) & 63;
        bf16x8 n10 = *(const bf16x8*)(w1l + (k2*32 + lo)*32 + hi*8);
        bf16x8 n11 = *(const bf16x8*)(w1l + (k2*32 + 16 + lo)*32 + hi*8);
        bf16x8 n20 = *(const bf16x8*)(w2l + (lo)*2048 + k2*32 + hi*8);
        bf16x8 n21 = *(const bf16x8*)(w2l + (16 + lo)*2048 + k2*32 + hi*8);
        f32x4  nb0 = *(const f32x4*)(b1l + k2*32 + hi*4);
        f32x4  nb1 = *(const f32x4*)(b1l + k2*32 + 16 + hi*4);
        #pragma unroll
        for (int si = 0; si < NS; ++si) {
          f32x4 d0 = MFMA32(A10, bh[si], Ab0);  // m[hid=kk32+4hi+r][tok=lo]
          f32x4 d1 = MFMA32(A11, bh[si], Ab1);
          bf16x4 m0, m1;
          #pragma unroll
          for (int r = 0; r < 4; ++r) {
            m0[r] = (bf16)fmaxf(d0[r], 0.f);
            m1[r] = (bf16)fmaxf(d1[r], 0.f);
          }
          *(bf16x4*)(&mbuf[wv][si][lo][hi*4])      = m0;   // window 0
          *(bf16x4*)(&mbuf[wv][si][lo][16 + hi*4]) = m1;
        }
        LDS_FENCE();                    // compiler order only; HW LDS is in-order per wave
        #pragma unroll
        for (int si = 0; si < NS; ++si) {
          bf16x8 am = *(const bf16x8*)(&mbuf[wv][si][lo][hi*8]);
          acc2[si][0] = MFMA32(am, A20, acc2[si][0]);
          acc2[si][1] = MFMA32(am, A21, acc2[si][1]);
        }
        A10 = n10; A11 = n11; A20 = n20; A21 = n21; Ab0 = nb0; Ab1 = nb1;
      }
      // ======== odd half: uses set B (window 32); prefetch B <- kk+3 ========
      {
        const int k3 = (kk + 3) & 63;
        bf16x8 n10 = *(const bf16x8*)(w1l + (k3*32 + lo)*32 + hi*8);
        bf16x8 n11 = *(const bf16x8*)(w1l + (k3*32 + 16 + lo)*32 + hi*8);
        bf16x8 n20 = *(const bf16x8*)(w2l + (lo)*2048 + k3*32 + hi*8);
        bf16x8 n21 = *(const bf16x8*)(w2l + (16 + lo)*2048 + k3*32 + hi*8);
        f32x4  nb0 = *(const f32x4*)(b1l + k3*32 + hi*4);
        f32x4  nb1 = *(const f32x4*)(b1l + k3*32 + 16 + hi*4);
        #pragma unroll
        for (int si = 0; si < NS; ++si) {
          f32x4 d0 = MFMA32(B10, bh[si], Bb0);
          f32x4 d1 = MFMA32(B11, bh[si], Bb1);
          bf16x4 m0, m1;
          #pragma unroll
          for (int r = 0; r < 4; ++r) {
            m0[r] = (bf16)fmaxf(d0[r], 0.f);
            m1[r] = (bf16)fmaxf(d1[r], 0.f);
          }
          *(bf16x4*)(&mbuf[wv][si][lo][32 + hi*4])      = m0;   // window 32
          *(bf16x4*)(&mbuf[wv][si][lo][32 + 16 + hi*4]) = m1;
        }
        LDS_FENCE();
        #pragma unroll
        for (int si = 0; si < NS; ++si) {
          bf16x8 am = *(const bf16x8*)(&mbuf[wv][si][lo][32 + hi*8]);
          acc2[si][0] = MFMA32(am, B20, acc2[si][0]);
          acc2[si][1] = MFMA32(am, B21, acc2[si][1]);
        }
        B10 = n10; B11 = n11; B20 = n20; B21 = n21; Bb0 = nb0; Bb1 = nb1;
      }
    }
    // ---- residual + LN(gm,bm) (b2 already in acc2); rebuild bh ----
    {
      float g0 = gm[l*32 + lo], g1 = gm[l*32 + 16 + lo];
      float a0 = bm[l*32 + lo], a1 = bm[l*32 + 16 + lo];
      #pragma unroll
      for (int si = 0; si < NS; ++si) {
        bf16x4 nh0, nh1;
        #pragma unroll
        for (int r = 0; r < 4; ++r) {
          float v0 = acc2[si][0][r] + (float)hD0[si][r];
          float v1 = acc2[si][1][r] + (float)hD1[si][r];
          float s1 = v0 + v1, s2 = v0*v0 + v1*v1;
          s1 += __shfl_xor(s1, 1); s2 += __shfl_xor(s2, 1);
          s1 += __shfl_xor(s1, 2); s2 += __shfl_xor(s2, 2);
          s1 += __shfl_xor(s1, 4); s2 += __shfl_xor(s2, 4);
          s1 += __shfl_xor(s1, 8); s2 += __shfl_xor(s2, 8);
          float mean = s1 * (1.f/32.f);
          float var  = s2 * (1.f/32.f) - mean*mean;
          float rs   = rsqrtf(fabsf(var) + 1e-5f);
          float h0 = (v0 - mean)*rs*g0 + a0;
          float h1 = (v1 - mean)*rs*g1 + a1;
          nh0[r] = (bf16)h0; nh1[r] = (bf16)h1;
          hbnc[wv][si][hi*4 + r][lo]      = (bf16)h0;
          hbnc[wv][si][hi*4 + r][16 + lo] = (bf16)h1;
        }
        hD0[si] = nh0; hD1[si] = nh1;
      }
      LDS_FENCE();
      #pragma unroll
      for (int si = 0; si < NS; ++si)
        bh[si] = *(const bf16x8*)(&hbnc[wv][si][lo][hi*8]);
      LDS_FENCE();
    }
  }

  // ---- final classifier: batch-loaded Wf; h @ Wf + bf (bias in C) -> out (f32) ----
  {
    bf16x8 wf8[5];
    f32x4 cb[5];
    #pragma unroll
    for (int nt = 0; nt < 5; ++nt) {
      wf8[nt] = *(const bf16x8*)(wfT + (nt*16 + lo)*32 + hi*8);
      int col = nt*16 + lo;
      cb[nt] = splat4((col < VOC) ? bfin[col] : 0.f);
    }
    #pragma unroll
    for (int si = 0; si < NS; ++si) {
      const int s = seq0 + si;
      bf16x8 a = bh[si];
      #pragma unroll
      for (int nt = 0; nt < 5; ++nt) {
        int col = nt*16 + lo;
        f32x4 d = MFMA32(a, wf8[nt], cb[nt]);   // D[tok=4hi+r][voc=nt16+lo]
        if (col < VOC) {
          #pragma unroll
          for (int r = 0; r < 4; ++r)
            out[(s*16 + hi*4 + r)*VOC + col] = d[r];
        }
      }
    }
  }
}

extern "C" void kernel_launch(void* const* d_in, const int* in_sizes, int n_in,
                              void* d_out, int out_size, void* d_ws, size_t ws_size,
                              hipStream_t stream) {
  const int*   x   = (const int*)d_in[0];
  const float* emb = (const float*)d_in[1];
  const float* pos = (const float*)d_in[2];
  const float* Wq  = (const float*)d_in[3];
  const float* bq  = (const float*)d_in[4];
  const float* Wk  = (const float*)d_in[5];
  const float* bk  = (const float*)d_in[6];
  const float* Wv  = (const float*)d_in[7];
  const float* bv  = (const float*)d_in[8];
  const float* Wo  = (const float*)d_in[9];
  const float* bo  = (const float*)d_in[10];
  const float* ga  = (const float*)d_in[11];
  const float* ba  = (const float*)d_in[12];
  const float* W1  = (const float*)d_in[13];
  const float* b1  = (const float*)d_in[14];
  const float* W2  = (const float*)d_in[15];
  const float* b2  = (const float*)d_in[16];
  const float* gm  = (const float*)d_in[17];
  const float* bm  = (const float*)d_in[18];
  const float* Wf  = (const float*)d_in[19];
  const float* bfin= (const float*)d_in[20];

  bf16* ws = (bf16*)d_ws;

  // transpose weights (f32 -> bf16) into MFMA [out][k] layout (k contiguous)
  transpose_f32bf16_k<<<64, 256, 0, stream>>>(Wq, ws + WS_WQ, 8, 32, 64);
  transpose_f32bf16_k<<<64, 256, 0, stream>>>(Wk, ws + WS_WK, 8, 32, 64);
  transpose_f32bf16_k<<<64, 256, 0, stream>>>(Wv, ws + WS_WV, 8, 32, 64);
  transpose_f32bf16_k<<<64, 256, 0, stream>>>(Wo, ws + WS_WO, 2, 256, 32);
  transpose_f32bf16_k<<<512, 256, 0, stream>>>(W1, ws + WS_W1, 2, 32, 2048);
  transpose_f32bf16_k<<<512, 256, 0, stream>>>(W2, ws + WS_W2, 2, 2048, 32);
  prep_wf_k<<<10, 256, 0, stream>>>(Wf, ws + WS_WF);

  // fused transformer: 512 blocks x 128 threads (2 waves x 4 seqs)
  xformer_k<<<512, 128, 0, stream>>>(x, emb, pos, bq, bk, bv, bo, ga, ba,
                                     b1, b2, gm, bm, bfin,
                                     ws, (float*)d_out);
}

// Round 22
// 132.541 us; speedup vs baseline: 1.2779x; 1.2779x over previous
//
#include <hip/hip_runtime.h>

typedef __bf16 bf16;
typedef __bf16 bf16x4 __attribute__((ext_vector_type(4)));
typedef __bf16 bf16x8 __attribute__((ext_vector_type(8)));
typedef short  s16x4  __attribute__((ext_vector_type(4)));
typedef float  f32x4  __attribute__((ext_vector_type(4)));

#define VOC 65

// Compiler-only ordering barrier. HW executes a wave's LDS ops in program
// order, so ds_write -> ds_read (same wave) needs no lgkmcnt drain; the
// compiler auto-inserts result-waits for each read's consumer.
#define LDS_FENCE() asm volatile("" ::: "memory")

// workspace layout (element offsets, bf16)
#define WS_WQ 0
#define WS_WK 16384
#define WS_WV 32768
#define WS_WO 49152
#define WS_W1 65536
#define WS_W2 196608
#define WS_WF 327680   // padded [80][32]

// ---------------- prep kernels: f32 -> bf16 transpose to [col][k] (k contiguous) ----------------
__global__ void transpose_f32bf16_k(const float* __restrict__ src, bf16* __restrict__ dst,
                                    int batch, int R, int C) {
  int i = blockIdx.x * blockDim.x + threadIdx.x;
  int total = batch * R * C;
  if (i >= total) return;
  int b = i / (R * C);
  int rc = i - b * (R * C);
  int r = rc / C;
  int c = rc - r * C;
  dst[(b * C + c) * R + r] = (bf16)src[i];   // [b][R][C] -> [b][C][R]
}

__global__ void prep_wf_k(const float* __restrict__ wf, bf16* __restrict__ dst) {
  int i = blockIdx.x * blockDim.x + threadIdx.x;  // 80*32
  if (i >= 80 * 32) return;
  int c = i >> 5, r = i & 31;
  dst[i] = (c < VOC) ? (bf16)wf[r * VOC + c] : (bf16)0.0f;  // [80 cols][32 k], cols 65..79 zero
}

// ---------------- fused transformer ----------------
// R22 = R20 champion verbatim: register-chained attention (NS=4, 1 wave/SIMD),
// LDS-bounce FFN with 2-deep prefetch, compiler-only fences, no-max softmax,
// bias-in-C. 132.8 us measured.

#define MFMA32(a,b,c) __builtin_amdgcn_mfma_f32_16x16x32_bf16((a),(b),(c),0,0,0)

static __device__ __forceinline__ f32x4 MFMA16(bf16x4 a, bf16x4 b, f32x4 c) {
  return __builtin_amdgcn_mfma_f32_16x16x16bf16_1k(
      __builtin_bit_cast(s16x4, a), __builtin_bit_cast(s16x4, b), c, 0, 0, 0);
}

static __device__ __forceinline__ f32x4 splat4(float v) {
  f32x4 s; s[0] = v; s[1] = v; s[2] = v; s[3] = v; return s;
}

#define NS 4   // seqs per wave

__global__ __launch_bounds__(128)
void xformer_k(const int* __restrict__ x, const float* __restrict__ emb, const float* __restrict__ pos,
               const float* __restrict__ bq, const float* __restrict__ bk, const float* __restrict__ bv,
               const float* __restrict__ bo, const float* __restrict__ ga, const float* __restrict__ ba,
               const float* __restrict__ b1, const float* __restrict__ b2,
               const float* __restrict__ gm, const float* __restrict__ bm,
               const float* __restrict__ bfin,
               const bf16* __restrict__ ws, float* __restrict__ out)
{
  __shared__ bf16 mbuf[2][NS][16][72];  // [wave][si][tok][hid], two 32-col parity windows
  __shared__ bf16 hbnc[2][NS][16][40];  // [wave][si][tok][dim] LN transpose bounce
  const int tid  = threadIdx.x;
  const int wv   = tid >> 6;
  const int lane = tid & 63;
  const int lo   = lane & 15;
  const int hi   = lane >> 4;           // 0..3
  const int seq0 = blockIdx.x * (2*NS) + wv * NS;

  const bf16* wqT = ws + WS_WQ;         // [l*4+h][64 out][32 k]
  const bf16* wkT = ws + WS_WK;
  const bf16* wvT = ws + WS_WV;
  const bf16* woT = ws + WS_WO;         // [l][32 out][256 hv]
  const bf16* w1T = ws + WS_W1;         // [l][2048 hid][32 k]
  const bf16* w2T = ws + WS_W2;         // [l][32 out][2048 hid]
  const bf16* wfT = ws + WS_WF;         // [80 voc][32 k]

  const f32x4 fz = {0.f, 0.f, 0.f, 0.f};

  // Register state per seq:
  //  bh : h as MFMA32 A/B-frag  [tok=lo][dim=hi*8+j]
  //  hD0: h[tok=4hi+r][dim=lo], hD1: [dim=16+lo]  (residual copy, D-layout)
  bf16x8 bh[NS];
  bf16x4 hD0[NS], hD1[NS];

  // ---- embedding: h = (emb[x] + pos) * sqrt(32), straight to registers ----
  #pragma unroll
  for (int si = 0; si < NS; ++si) {
    const int s = seq0 + si;
    int idl = x[s*16 + lo];
    idl = idl < 0 ? 0 : (idl >= VOC ? VOC - 1 : idl);
    f32x4 e0 = *(const f32x4*)(emb + idl*32 + hi*8);
    f32x4 e1 = *(const f32x4*)(emb + idl*32 + hi*8 + 4);
    f32x4 p0 = *(const f32x4*)(pos + lo*32 + hi*8);
    f32x4 p1 = *(const f32x4*)(pos + lo*32 + hi*8 + 4);
    bf16x8 hv;
    #pragma unroll
    for (int j = 0; j < 4; ++j) {
      hv[j]   = (bf16)((e0[j] + p0[j]) * 5.656854249492381f);
      hv[4+j] = (bf16)((e1[j] + p1[j]) * 5.656854249492381f);
    }
    bh[si] = hv;
    bf16x4 d0, d1;
    #pragma unroll
    for (int r = 0; r < 4; ++r) {
      int tr = hi*4 + r;
      int idr = x[s*16 + tr];
      idr = idr < 0 ? 0 : (idr >= VOC ? VOC - 1 : idr);
      d0[r] = (bf16)((emb[idr*32 + lo]      + pos[tr*32 + lo])      * 5.656854249492381f);
      d1[r] = (bf16)((emb[idr*32 + 16 + lo] + pos[tr*32 + 16 + lo]) * 5.656854249492381f);
    }
    hD0[si] = d0; hD1[si] = d1;
  }

  for (int l = 0; l < 2; ++l) {
    // ================= attention: all-register =================
    f32x4 accO[NS][2];                  // D: [tok=4hi+r][out=n2*16+lo], bo in C
    {
      float bo0 = bo[l*32 + lo], bo1 = bo[l*32 + 16 + lo];
      #pragma unroll
      for (int si = 0; si < NS; ++si) { accO[si][0] = splat4(bo0); accO[si][1] = splat4(bo1); }
    }
    #pragma unroll
    for (int hh = 0; hh < 4; ++hh) {
      const int hb = (l*4 + hh) * 64;
      // ---- Q,K proj (swapped MFMA32, bias in C) fused into scores (MFMA16 chain) ----
      f32x4 sf[NS];
      #pragma unroll
      for (int si = 0; si < NS; ++si) sf[si] = fz;
      #pragma unroll
      for (int nt = 0; nt < 4; ++nt) {
        const int wofs = (hb + nt*16 + lo)*32 + hi*8;
        bf16x8 wq8 = *(const bf16x8*)(wqT + wofs);
        bf16x8 wk8 = *(const bf16x8*)(wkT + wofs);
        f32x4 bq4 = *(const f32x4*)(bq + hb + nt*16 + hi*4);
        f32x4 bk4 = *(const f32x4*)(bk + hb + nt*16 + hi*4);
        #pragma unroll
        for (int si = 0; si < NS; ++si) {
          f32x4 dq = MFMA32(wq8, bh[si], bq4);  // Q[out=nt16+4hi+r][tok=lo]
          f32x4 dk = MFMA32(wk8, bh[si], bk4);
          bf16x4 pq, pk;
          #pragma unroll
          for (int r = 0; r < 4; ++r) {
            pq[r] = (bf16)dq[r];
            pk[r] = (bf16)dk[r];
          }
          sf[si] = MFMA16(pk, pq, sf[si]);      // S[key=4hi+r][query=lo]
        }
      }
      // ---- softmax (no-max: scores are O(1), exp cannot overflow; mask -> exp(-30)~0) ----
      bf16x4 pp[NS];
      #pragma unroll
      for (int si = 0; si < NS; ++si) {
        float e[4], sm = 0.f;
        #pragma unroll
        for (int r = 0; r < 4; ++r) {
          int key = hi*4 + r;
          float v0 = (key <= lo) ? sf[si][r] * 0.125f : -30.0f;
          e[r] = __expf(v0);
          sm += e[r];
        }
        sm += __shfl_xor(sm, 16);
        sm += __shfl_xor(sm, 32);
        float inv = 1.0f / sm;
        bf16x4 p4;
        #pragma unroll
        for (int r = 0; r < 4; ++r) p4[r] = (bf16)(e[r] * inv);
        pp[si] = p4;                            // B-frag [col=query=lo][k=key 4hi+j]
      }
      // ---- V proj (original, bias in C) + PV + out-proj (register-chained) ----
      #pragma unroll
      for (int nt = 0; nt < 4; ++nt) {
        bf16x8 wv8 = *(const bf16x8*)(wvT + (hb + nt*16 + lo)*32 + hi*8);
        f32x4 bv4 = splat4(bv[hb + nt*16 + lo]);
        bf16x4 wo4[2];
        #pragma unroll
        for (int n2 = 0; n2 < 2; ++n2)
          wo4[n2] = *(const bf16x4*)(woT + (l*32 + n2*16 + lo)*256 + hh*64 + nt*16 + hi*4);
        #pragma unroll
        for (int si = 0; si < NS; ++si) {
          f32x4 dv = MFMA32(bh[si], wv8, bv4);  // V[tok=4hi+r][vdim=nt16+lo]
          bf16x4 vz;
          #pragma unroll
          for (int r = 0; r < 4; ++r) vz[r] = (bf16)dv[r];
          f32x4 o = MFMA16(vz, pp[si], fz);     // O[vdim=nt16+4hi+r][tok=lo]
          bf16x4 oz;
          #pragma unroll
          for (int r = 0; r < 4; ++r) oz[r] = (bf16)o[r];
          #pragma unroll
          for (int n2 = 0; n2 < 2; ++n2)
            accO[si][n2] = MFMA16(oz, wo4[n2], accO[si][n2]);  // [tok=4hi+r][out=n2*16+lo]
        }
      }
    }
    // ---- residual + LN(ga,ba) (bo already in accO); rebuild bh via wave-private bounce ----
    {
      float g0 = ga[l*32 + lo], g1 = ga[l*32 + 16 + lo];
      float a0 = ba[l*32 + lo], a1 = ba[l*32 + 16 + lo];
      #pragma unroll
      for (int si = 0; si < NS; ++si) {
        bf16x4 nh0, nh1;
        #pragma unroll
        for (int r = 0; r < 4; ++r) {
          float v0 = accO[si][0][r] + (float)hD0[si][r];
          float v1 = accO[si][1][r] + (float)hD1[si][r];
          float s1 = v0 + v1, s2 = v0*v0 + v1*v1;
          s1 += __shfl_xor(s1, 1); s2 += __shfl_xor(s2, 1);
          s1 += __shfl_xor(s1, 2); s2 += __shfl_xor(s2, 2);
          s1 += __shfl_xor(s1, 4); s2 += __shfl_xor(s2, 4);
          s1 += __shfl_xor(s1, 8); s2 += __shfl_xor(s2, 8);
          float mean = s1 * (1.f/32.f);
          float var  = s2 * (1.f/32.f) - mean*mean;
          float rs   = rsqrtf(fabsf(var) + 1e-5f);
          float h0 = (v0 - mean)*rs*g0 + a0;
          float h1 = (v1 - mean)*rs*g1 + a1;
          nh0[r] = (bf16)h0; nh1[r] = (bf16)h1;
          hbnc[wv][si][hi*4 + r][lo]      = (bf16)h0;
          hbnc[wv][si][hi*4 + r][16 + lo] = (bf16)h1;
        }
        hD0[si] = nh0; hD1[si] = nh1;
      }
      LDS_FENCE();
      #pragma unroll
      for (int si = 0; si < NS; ++si)
        bh[si] = *(const bf16x8*)(&hbnc[wv][si][lo][hi*8]);
      LDS_FENCE();
    }
    // ================= FFN: LDS-bounce MFMA32, 2-deep prefetch, unroll-2 =================
    f32x4 acc2[NS][2];                  // D: [tok=4hi+r][out=n2*16+lo], b2 in C
    {
      float b20 = b2[l*32 + lo], b21 = b2[l*32 + 16 + lo];
      #pragma unroll
      for (int si = 0; si < NS; ++si) { acc2[si][0] = splat4(b20); acc2[si][1] = splat4(b21); }
    }
    const bf16* w1l = w1T + l*65536;
    const bf16* w2l = w2T + l*65536;
    const float* b1l = b1 + l*2048;
    // preload set A (kk=0) and set B (kk=1)
    bf16x8 A10 = *(const bf16x8*)(w1l + (lo)*32 + hi*8);
    bf16x8 A11 = *(const bf16x8*)(w1l + (16 + lo)*32 + hi*8);
    bf16x8 A20 = *(const bf16x8*)(w2l + (lo)*2048 + hi*8);
    bf16x8 A21 = *(const bf16x8*)(w2l + (16 + lo)*2048 + hi*8);
    f32x4  Ab0 = *(const f32x4*)(b1l + hi*4);
    f32x4  Ab1 = *(const f32x4*)(b1l + 16 + hi*4);
    bf16x8 B10 = *(const bf16x8*)(w1l + (32 + lo)*32 + hi*8);
    bf16x8 B11 = *(const bf16x8*)(w1l + (48 + lo)*32 + hi*8);
    bf16x8 B20 = *(const bf16x8*)(w2l + (lo)*2048 + 32 + hi*8);
    bf16x8 B21 = *(const bf16x8*)(w2l + (16 + lo)*2048 + 32 + hi*8);
    f32x4  Bb0 = *(const f32x4*)(b1l + 32 + hi*4);
    f32x4  Bb1 = *(const f32x4*)(b1l + 32 + 16 + hi*4);
    for (int kk = 0; kk < 64; kk += 2) {
      // ======== even half: uses set A (window 0); prefetch A <- kk+2 ========
      {
        const int k2 = (kk + 2) & 63;
        bf16x8 n10 = *(const bf16x8*)(w1l + (k2*32 + lo)*32 + hi*8);
        bf16x8 n11 = *(const bf16x8*)(w1l + (k2*32 + 16 + lo)*32 + hi*8);
        bf16x8 n20 = *(const bf16x8*)(w2l + (lo)*2048 + k2*32 + hi*8);
        bf16x8 n21 = *(const bf16x8*)(w2l + (16 + lo)*2048 + k2*32 + hi*8);
        f32x4  nb0 = *(const f32x4*)(b1l + k2*32 + hi*4);
        f32x4  nb1 = *(const f32x4*)(b1l + k2*32 + 16 + hi*4);
        #pragma unroll
        for (int si = 0; si < NS; ++si) {
          f32x4 d0 = MFMA32(A10, bh[si], Ab0);  // m[hid=kk32+4hi+r][tok=lo]
          f32x4 d1 = MFMA32(A11, bh[si], Ab1);
          bf16x4 m0, m1;
          #pragma unroll
          for (int r = 0; r < 4; ++r) {
            m0[r] = (bf16)fmaxf(d0[r], 0.f);
            m1[r] = (bf16)fmaxf(d1[r], 0.f);
          }
          *(bf16x4*)(&mbuf[wv][si][lo][hi*4])      = m0;   // window 0
          *(bf16x4*)(&mbuf[wv][si][lo][16 + hi*4]) = m1;
        }
        LDS_FENCE();                    // compiler order only; HW LDS is in-order per wave
        #pragma unroll
        for (int si = 0; si < NS; ++si) {
          bf16x8 am = *(const bf16x8*)(&mbuf[wv][si][lo][hi*8]);
          acc2[si][0] = MFMA32(am, A20, acc2[si][0]);
          acc2[si][1] = MFMA32(am, A21, acc2[si][1]);
        }
        A10 = n10; A11 = n11; A20 = n20; A21 = n21; Ab0 = nb0; Ab1 = nb1;
      }
      // ======== odd half: uses set B (window 32); prefetch B <- kk+3 ========
      {
        const int k3 = (kk + 3) & 63;
        bf16x8 n10 = *(const bf16x8*)(w1l + (k3*32 + lo)*32 + hi*8);
        bf16x8 n11 = *(const bf16x8*)(w1l + (k3*32 + 16 + lo)*32 + hi*8);
        bf16x8 n20 = *(const bf16x8*)(w2l + (lo)*2048 + k3*32 + hi*8);
        bf16x8 n21 = *(const bf16x8*)(w2l + (16 + lo)*2048 + k3*32 + hi*8);
        f32x4  nb0 = *(const f32x4*)(b1l + k3*32 + hi*4);
        f32x4  nb1 = *(const f32x4*)(b1l + k3*32 + 16 + hi*4);
        #pragma unroll
        for (int si = 0; si < NS; ++si) {
          f32x4 d0 = MFMA32(B10, bh[si], Bb0);
          f32x4 d1 = MFMA32(B11, bh[si], Bb1);
          bf16x4 m0, m1;
          #pragma unroll
          for (int r = 0; r < 4; ++r) {
            m0[r] = (bf16)fmaxf(d0[r], 0.f);
            m1[r] = (bf16)fmaxf(d1[r], 0.f);
          }
          *(bf16x4*)(&mbuf[wv][si][lo][32 + hi*4])      = m0;   // window 32
          *(bf16x4*)(&mbuf[wv][si][lo][32 + 16 + hi*4]) = m1;
        }
        LDS_FENCE();
        #pragma unroll
        for (int si = 0; si < NS; ++si) {
          bf16x8 am = *(const bf16x8*)(&mbuf[wv][si][lo][32 + hi*8]);
          acc2[si][0] = MFMA32(am, B20, acc2[si][0]);
          acc2[si][1] = MFMA32(am, B21, acc2[si][1]);
        }
        B10 = n10; B11 = n11; B20 = n20; B21 = n21; Bb0 = nb0; Bb1 = nb1;
      }
    }
    // ---- residual + LN(gm,bm) (b2 already in acc2); rebuild bh ----
    {
      float g0 = gm[l*32 + lo], g1 = gm[l*32 + 16 + lo];
      float a0 = bm[l*32 + lo], a1 = bm[l*32 + 16 + lo];
      #pragma unroll
      for (int si = 0; si < NS; ++si) {
        bf16x4 nh0, nh1;
        #pragma unroll
        for (int r = 0; r < 4; ++r) {
          float v0 = acc2[si][0][r] + (float)hD0[si][r];
          float v1 = acc2[si][1][r] + (float)hD1[si][r];
          float s1 = v0 + v1, s2 = v0*v0 + v1*v1;
          s1 += __shfl_xor(s1, 1); s2 += __shfl_xor(s2, 1);
          s1 += __shfl_xor(s1, 2); s2 += __shfl_xor(s2, 2);
          s1 += __shfl_xor(s1, 4); s2 += __shfl_xor(s2, 4);
          s1 += __shfl_xor(s1, 8); s2 += __shfl_xor(s2, 8);
          float mean = s1 * (1.f/32.f);
          float var  = s2 * (1.f/32.f) - mean*mean;
          float rs   = rsqrtf(fabsf(var) + 1e-5f);
          float h0 = (v0 - mean)*rs*g0 + a0;
          float h1 = (v1 - mean)*rs*g1 + a1;
          nh0[r] = (bf16)h0; nh1[r] = (bf16)h1;
          hbnc[wv][si][hi*4 + r][lo]      = (bf16)h0;
          hbnc[wv][si][hi*4 + r][16 + lo] = (bf16)h1;
        }
        hD0[si] = nh0; hD1[si] = nh1;
      }
      LDS_FENCE();
      #pragma unroll
      for (int si = 0; si < NS; ++si)
        bh[si] = *(const bf16x8*)(&hbnc[wv][si][lo][hi*8]);
      LDS_FENCE();
    }
  }

  // ---- final classifier: h @ Wf + bf (bias in C) -> out [s,16,65] (f32) ----
  #pragma unroll
  for (int si = 0; si < NS; ++si) {
    const int s = seq0 + si;
    bf16x8 a = bh[si];
    #pragma unroll
    for (int nt = 0; nt < 5; ++nt) {
      int col = nt*16 + lo;
      f32x4 cb = splat4((col < VOC) ? bfin[col] : 0.f);
      bf16x8 w = *(const bf16x8*)(wfT + (nt*16 + lo)*32 + hi*8);
      f32x4 d = MFMA32(a, w, cb);       // D[tok=4hi+r][voc=nt16+lo]
      if (col < VOC) {
        #pragma unroll
        for (int r = 0; r < 4; ++r)
          out[(s*16 + hi*4 + r)*VOC + col] = d[r];
      }
    }
  }
}

extern "C" void kernel_launch(void* const* d_in, const int* in_sizes, int n_in,
                              void* d_out, int out_size, void* d_ws, size_t ws_size,
                              hipStream_t stream) {
  const int*   x   = (const int*)d_in[0];
  const float* emb = (const float*)d_in[1];
  const float* pos = (const float*)d_in[2];
  const float* Wq  = (const float*)d_in[3];
  const float* bq  = (const float*)d_in[4];
  const float* Wk  = (const float*)d_in[5];
  const float* bk  = (const float*)d_in[6];
  const float* Wv  = (const float*)d_in[7];
  const float* bv  = (const float*)d_in[8];
  const float* Wo  = (const float*)d_in[9];
  const float* bo  = (const float*)d_in[10];
  const float* ga  = (const float*)d_in[11];
  const float* ba  = (const float*)d_in[12];
  const float* W1  = (const float*)d_in[13];
  const float* b1  = (const float*)d_in[14];
  const float* W2  = (const float*)d_in[15];
  const float* b2  = (const float*)d_in[16];
  const float* gm  = (const float*)d_in[17];
  const float* bm  = (const float*)d_in[18];
  const float* Wf  = (const float*)d_in[19];
  const float* bfin= (const float*)d_in[20];

  bf16* ws = (bf16*)d_ws;

  // transpose weights (f32 -> bf16) into MFMA [out][k] layout (k contiguous)
  transpose_f32bf16_k<<<64, 256, 0, stream>>>(Wq, ws + WS_WQ, 8, 32, 64);
  transpose_f32bf16_k<<<64, 256, 0, stream>>>(Wk, ws + WS_WK, 8, 32, 64);
  transpose_f32bf16_k<<<64, 256, 0, stream>>>(Wv, ws + WS_WV, 8, 32, 64);
  transpose_f32bf16_k<<<64, 256, 0, stream>>>(Wo, ws + WS_WO, 2, 256, 32);
  transpose_f32bf16_k<<<512, 256, 0, stream>>>(W1, ws + WS_W1, 2, 32, 2048);
  transpose_f32bf16_k<<<512, 256, 0, stream>>>(W2, ws + WS_W2, 2, 2048, 32);
  prep_wf_k<<<10, 256, 0, stream>>>(Wf, ws + WS_WF);

  // fused transformer: 512 blocks x 128 threads (2 waves x 4 seqs)
  xformer_k<<<512, 128, 0, stream>>>(x, emb, pos, bq, bk, bv, bo, ga, ba,
                                     b1, b2, gm, bm, bfin,
                                     ws, (float*)d_out);
}